// Round 15
// baseline (223.435 us; speedup 1.0000x reference)
//
#include <hip/hip_runtime.h>
#include <stdint.h>

#define B_ 8
#define D_ 256
#define T_ 2048
#define K_ 8192
#define N_ (B_*T_)   // 16384

typedef __attribute__((ext_vector_type(8))) __bf16 bf16x8;
typedef __attribute__((ext_vector_type(4))) __bf16 bf16x4;
typedef __attribute__((ext_vector_type(2))) __bf16 bf16x2;
typedef __attribute__((ext_vector_type(4))) float f32x4;

// ---------------- workspace layout ----------------
// best: u64[N]   off 0         (131072 B)
// cs:   int[K]   off 131072    (32768 B)
// dw:   f32[K*D] off 163840    (8388608 B)
// sse:  f32[K]   off 8552448   (32768 B)
// ssx:  f32[N]   off 8585216   (65536 B)
// K-slot-major panels in d_out (scratch until scatter runs):
//   X3 = [16 ph][4 s][16384 rows][8 bf16] (16.78 MB) at out+0
//        flat kslot panels: Xh = 0..31, Xl = 32..63
//   E3 = [16 ph][4 s][8192 rows][8 bf16]  (8.39 MB)  at out+32MB
//        flat panels: El = ph 0-7, Eh = ph 8-15
// R14 dist: 16 fused phases. Phases 0-7 (El kh): El(kh)·Xh(kh), 32 MFMA.
// Phases 8-15 (Eh kh): A-Eh staged ONCE, af[] held in regs: Eh(kh)·Xl(kh)
// then Eh(kh)·Xh(kh), 64 MFMA. Cuts A staging+reads by 1/3 vs R13.
// Per-acc fp32 add order: El·Xh kh0-7, then (Eh·Xl, Eh·Xh) per kh 0-7 —
// ulp-class reorder of R13's grouped order (same class as R2->R5 reorders).

__global__ __launch_bounds__(256) void prep_e_kernel(const float* __restrict__ E,
                                                     __bf16* __restrict__ E3,
                                                     float* __restrict__ sse) {
    int row  = blockIdx.x * 4 + (threadIdx.x >> 6);
    int lane = threadIdx.x & 63;
    int d    = lane * 4;
    float4 v = *(const float4*)(E + (size_t)row * D_ + d);
    __bf16 h0 = (__bf16)v.x, h1 = (__bf16)v.y, h2 = (__bf16)v.z, h3 = (__bf16)v.w;
    __bf16 l0 = (__bf16)(v.x - (float)h0), l1 = (__bf16)(v.y - (float)h1);
    __bf16 l2 = (__bf16)(v.z - (float)h2), l3 = (__bf16)(v.w - (float)h3);
    bf16x4 hv = {h0, h1, h2, h3};
    bf16x4 lv = {l0, l1, l2, l3};
    int kh  = d >> 5;            // k-half 0..7
    int s   = (d >> 3) & 3;      // kslot
    int pos = d & 7;             // 0 or 4
    *(bf16x4*)(E3 + ((size_t)((kh    ) * 4 + s) * K_ + row) * 8 + pos) = lv; // El
    *(bf16x4*)(E3 + ((size_t)((8 + kh) * 4 + s) * K_ + row) * 8 + pos) = hv; // Eh
    float sq = __fadd_rn(__fadd_rn(__fmul_rn(v.x, v.x), __fmul_rn(v.y, v.y)),
                         __fadd_rn(__fmul_rn(v.z, v.z), __fmul_rn(v.w, v.w)));
    #pragma unroll
    for (int off = 32; off > 0; off >>= 1) sq += __shfl_down(sq, off);
    if (lane == 0) sse[row] = sq;
}

__global__ __launch_bounds__(256) void prep_x_kernel(const float* __restrict__ x,
                                                     __bf16* __restrict__ X3,
                                                     float* __restrict__ ssx) {
    __shared__ float tile[64][65];
    __shared__ float part[64][4];
    int bidx = blockIdx.x;            // b(8) x dblk(4) x tblk(32)
    int b    = bidx >> 7;
    int dblk = (bidx >> 5) & 3;
    int tblk = bidx & 31;
    int d0 = dblk * 64, t0 = tblk * 64;
    const float* xp = x + (size_t)b * D_ * T_;
    {
        int tl = threadIdx.x & 63, th = threadIdx.x >> 6;
        float s = 0.f;
        #pragma unroll
        for (int i = 0; i < 16; i++) {
            int d = i * 4 + th;
            float v = xp[(size_t)(d0 + d) * T_ + t0 + tl];
            tile[d][tl] = v;
            s = __fadd_rn(s, __fmul_rn(v, v));
        }
        part[tl][th] = s;
    }
    __syncthreads();
    if (threadIdx.x < 64) {
        float tot = __fadd_rn(__fadd_rn(__fadd_rn(part[threadIdx.x][0],
                    part[threadIdx.x][1]), part[threadIdx.x][2]), part[threadIdx.x][3]);
        atomicAdd(ssx + b * T_ + t0 + threadIdx.x, tot);
    }
    // write phase: 16B-vector split writes
    {
        int t  = threadIdx.x & 63;
        int g0 = threadIdx.x >> 6;           // 0..3
        size_t n = (size_t)b * T_ + t0 + t;
        #pragma unroll
        for (int i = 0; i < 2; i++) {
            int dg = g0 + i * 4;             // 0..7 (8 d's each)
            int p  = (d0 >> 3) + dg;         // global k-slot panel index 0..31
            bf16x8 hv, lv;
            #pragma unroll
            for (int e = 0; e < 8; e++) {
                float v = tile[dg * 8 + e][t];
                __bf16 h = (__bf16)v;
                hv[e] = h;
                lv[e] = (__bf16)(v - (float)h);
            }
            *(bf16x8*)(X3 + ((size_t)(p     ) * N_ + n) * 8) = hv;  // Xh
            *(bf16x8*)(X3 + ((size_t)(p + 32) * N_ + n) * 8) = lv;  // Xl
        }
    }
}

// -------- 256(codes) x 128(xrows) fused-phase MFMA distance + argmin --------
// 2 slots x 32KB {A 16KB | B0 8KB | B1 8KB} = 64KB -> 2 blocks/CU.
// Depth-1 prefetch: stage(t+1) issued before compute(t); drain after MFMA.

#define GLD16(g, l) __builtin_amdgcn_global_load_lds(                           \
    (const __attribute__((address_space(1))) void*)(g),                         \
    (__attribute__((address_space(3))) void*)(l), 16, 0, 0)

#define VMW0() do { asm volatile("s_waitcnt vmcnt(0)" ::: "memory");            \
                    __builtin_amdgcn_sched_barrier(0); } while (0)
#define BAR() do { asm volatile("" ::: "memory");                               \
                   __builtin_amdgcn_s_barrier();                                \
                   asm volatile("" ::: "memory");                               \
                   __builtin_amdgcn_sched_barrier(0); } while (0)

// stage phase p (0-7 El, 8-15 Eh) into slot buf
__device__ __forceinline__ void stage_any(const __bf16* __restrict__ E3,
                                          const __bf16* __restrict__ X3,
                                          __bf16* smem, int p, int buf,
                                          int c0, int r0, int tid) {
    const int kh = p & 7;
    __bf16* slot = smem + buf * 16384;
    // A: El (p<8) or Eh (p>=8): flat panels (p*4 + s)
    __bf16* lA = slot + ((tid >> 6) << 9);
    const __bf16* gA = E3 + ((size_t)(p * 4) * K_ + c0 + tid) * 8;
    #pragma unroll
    for (int o = 0; o < 4; o++)
        GLD16(gA + (size_t)o * K_ * 8, lA + o * 2048);
    if (p < 8) {
        // B0 = Xh(kh): flat panels kh*4 + s
        __bf16* lB0 = slot + 8192 + ((tid >> 6) << 9);
        #pragma unroll
        for (int o = 0; o < 2; o++) {
            const __bf16* gB = X3 + ((size_t)(kh * 4 + 2 * o + (tid >> 7)) * N_
                                     + r0 + (tid & 127)) * 8;
            GLD16(gB, lB0 + o * 2048);
        }
    } else {
        // B0 = Xl(kh): flat panels 32 + kh*4 + s ; B1 = Xh(kh)
        __bf16* lB0 = slot + 8192 + ((tid >> 6) << 9);
        __bf16* lB1 = slot + 12288 + ((tid >> 6) << 9);
        #pragma unroll
        for (int o = 0; o < 2; o++) {
            const __bf16* gB0 = X3 + ((size_t)(32 + kh * 4 + 2 * o + (tid >> 7)) * N_
                                      + r0 + (tid & 127)) * 8;
            GLD16(gB0, lB0 + o * 2048);
            const __bf16* gB1 = X3 + ((size_t)(kh * 4 + 2 * o + (tid >> 7)) * N_
                                      + r0 + (tid & 127)) * 8;
            GLD16(gB1, lB1 + o * 2048);
        }
    }
}

__device__ __forceinline__ void mfma32(f32x4 acc[8][4], const bf16x8 (&af)[8],
                                       const bf16x8 (&bf)[4]) {
    __builtin_amdgcn_s_setprio(1);
    #pragma unroll
    for (int i = 0; i < 8; i++)
        #pragma unroll
        for (int j = 0; j < 4; j++)
            acc[i][j] = __builtin_amdgcn_mfma_f32_16x16x32_bf16(
                af[i], bf[j], acc[i][j], 0, 0, 0);
    __builtin_amdgcn_s_setprio(0);
}

__global__ __launch_bounds__(256, 2) void dist_kernel(
    const __bf16* __restrict__ E3, const __bf16* __restrict__ X3,
    const float* __restrict__ ssx, const float* __restrict__ sse,
    unsigned long long* __restrict__ best)
{
    __shared__ __bf16 smem[32768];   // 64 KB: 2 slots x {A 16K|B0 8K|B1 8K}

    const int tid = threadIdx.x;
    const int l   = tid & 63;
    const int w   = tid >> 6;        // 0..3
    const int wm  = w >> 1;          // code half (128 each)
    const int wn  = w & 1;           // xrow half (64 each)

    // L2-resident XCD mapping: XCD x owns c-tiles [4x,4x+4), c fastest.
    const int bid = blockIdx.x;      // 0..4095
    const int xq  = bid & 7;
    const int i_  = bid >> 3;        // 0..511
    const int c0  = (xq * 4 + (i_ & 3)) * 256;
    const int r0  = (i_ >> 2) * 128;

    f32x4 acc[8][4];
    #pragma unroll
    for (int i = 0; i < 8; i++)
        #pragma unroll
        for (int j = 0; j < 4; j++) acc[i][j] = (f32x4)0.f;

    stage_any(E3, X3, smem, 0, 0, c0, r0, tid);
    VMW0();
    BAR();

    #pragma unroll 1
    for (int t = 0; t < 16; t++) {
        const int buf = t & 1;
        if (t < 15) stage_any(E3, X3, smem, t + 1, buf ^ 1, c0, r0, tid);
        const __bf16* slot = smem + buf * 16384;
        const __bf16* pa = slot + (l >> 4) * 2048 + (wm * 128 + (l & 15)) * 8;
        const __bf16* pb0 = slot + 8192 + (l >> 4) * 1024 + (wn * 64 + (l & 15)) * 8;
        bf16x8 af[8], bf[4];
        #pragma unroll
        for (int i = 0; i < 8; i++) af[i] = *(const bf16x8*)(pa + i * 128);
        #pragma unroll
        for (int j = 0; j < 4; j++) bf[j] = *(const bf16x8*)(pb0 + j * 128);
        mfma32(acc, af, bf);                 // El·Xh  or  Eh·Xl
        if (t >= 8) {                        // Eh phase: reuse af for Xh
            const __bf16* pb1 = slot + 12288 + (l >> 4) * 1024
                                + (wn * 64 + (l & 15)) * 8;
            bf16x8 bg[4];
            #pragma unroll
            for (int j = 0; j < 4; j++) bg[j] = *(const bf16x8*)(pb1 + j * 128);
            mfma32(acc, af, bg);             // Eh·Xh
        }
        VMW0();                              // stage(t+1) landed (post-compute)
        BAR();
    }

    // epilogue: dist = (ssx + sse) - 2*dot, packed-u64 argmin (ties -> low idx)
    #pragma unroll
    for (int j = 0; j < 4; j++) {
        int xrow = r0 + wn * 64 + j * 16 + (l & 15);
        float sx = ssx[xrow];
        unsigned long long m = ~0ull;
        #pragma unroll
        for (int i = 0; i < 8; i++) {
            int cbase = c0 + wm * 128 + i * 16 + (l >> 4) * 4;
            float4 sc = *(const float4*)(sse + cbase);
            f32x4 a = acc[i][j];
            float d0 = (sx + sc.x) - 2.0f * a[0];
            float d1 = (sx + sc.y) - 2.0f * a[1];
            float d2 = (sx + sc.z) - 2.0f * a[2];
            float d3 = (sx + sc.w) - 2.0f * a[3];
            unsigned long long p;
            p = ((unsigned long long)__float_as_uint(d0) << 32) | (unsigned)(cbase + 0);
            if (p < m) m = p;
            p = ((unsigned long long)__float_as_uint(d1) << 32) | (unsigned)(cbase + 1);
            if (p < m) m = p;
            p = ((unsigned long long)__float_as_uint(d2) << 32) | (unsigned)(cbase + 2);
            if (p < m) m = p;
            p = ((unsigned long long)__float_as_uint(d3) << 32) | (unsigned)(cbase + 3);
            if (p < m) m = p;
        }
        unsigned long long o;
        o = __shfl_xor(m, 16); if (o < m) m = o;
        o = __shfl_xor(m, 32); if (o < m) m = o;
        if ((l >> 4) == 0) atomicMin(best + xrow, m);
    }
}

// tiled coalesced gather/copy/stats: block = 64 n's x 256 d's
__global__ __launch_bounds__(256) void scatter_kernel(
    const float* __restrict__ x, const float* __restrict__ E,
    const unsigned long long* __restrict__ best,
    float* __restrict__ out, int* __restrict__ cs, float* __restrict__ dw)
{
    __shared__ float tx[64][68];
    __shared__ float te[64][68];
    __shared__ int sidx[64];

    const int blk = blockIdx.x;
    const int b   = blk >> 5;
    const int t0  = (blk & 31) * 64;
    const int tid = threadIdx.x;
    const int n0  = b * T_ + t0;

    if (tid < 64) {
        int ix = (int)(best[n0 + tid] & 0xffffffffu);
        sidx[tid] = ix;
        atomicAdd(cs + ix, 1);
    }
    __syncthreads();

    const int t4   = (tid & 15) * 4;
    const int dg   = tid >> 4;
    const int l    = tid & 63;
    const int w    = tid >> 6;
    const int nsub = l >> 4;
    const int dl4  = (l & 15) * 4;

    float* o0 = out;
    float* o1 = out + (size_t)N_ * D_;
    float* o2 = out + 2 * (size_t)N_ * D_;

    for (int dc = 0; dc < 4; dc++) {
        const int d0 = dc * 64;
        #pragma unroll
        for (int r = 0; r < 4; r++) {
            int d = r * 16 + dg;
            size_t gi = ((size_t)(b * D_ + d0 + d)) * T_ + t0 + t4;
            float4 v = *(const float4*)(x + gi);
            *(float4*)&tx[d][t4] = v;
            *(float4*)(o1 + gi) = v;
        }
        #pragma unroll
        for (int i = 0; i < 4; i++) {
            int nl  = w * 16 + i * 4 + nsub;
            int row = sidx[nl];
            float4 ev = *(const float4*)(E + (size_t)row * D_ + d0 + dl4);
            te[dl4 + 0][nl] = ev.x;
            te[dl4 + 1][nl] = ev.y;
            te[dl4 + 2][nl] = ev.z;
            te[dl4 + 3][nl] = ev.w;
        }
        __syncthreads();
        #pragma unroll
        for (int r = 0; r < 4; r++) {
            int d = r * 16 + dg;
            float4 v = *(const float4*)&te[d][t4];
            size_t gi = ((size_t)(b * D_ + d0 + d)) * T_ + t0 + t4;
            *(float4*)(o0 + gi) = v;
            *(float4*)(o2 + gi) = v;
        }
        #pragma unroll
        for (int i = 0; i < 16; i++) {
            int nl = w * 16 + i;
            atomicAdd(dw + (size_t)sidx[nl] * D_ + d0 + l, tx[l][nl]);
        }
        __syncthreads();
    }
}

__global__ __launch_bounds__(256) void finalize_kernel(
    const int* __restrict__ cs, const float* __restrict__ dw,
    float* __restrict__ out3)
{
    int k = blockIdx.x;
    int d = threadIdx.x;
    const float C = 0.00999999977648258209228515625f;
    float c   = (float)cs[k];
    float ecs = (c * C) / C;
    float edw = (dw[(size_t)k * D_ + d] * C) / C;
    float n = 16384.0f;
    float denom = (ecs + 1e-5f) / (n + (float)K_ * 1e-5f) * n;
    out3[(size_t)k * D_ + d] = edw / denom;
}

extern "C" void kernel_launch(void* const* d_in, const int* in_sizes, int n_in,
                              void* d_out, int out_size, void* d_ws, size_t ws_size,
                              hipStream_t stream) {
    const float* x = (const float*)d_in[0];
    const float* E = (const float*)d_in[1];
    float* out = (float*)d_out;

    char* ws = (char*)d_ws;
    unsigned long long* best = (unsigned long long*)(ws);
    int*   cs  = (int*)  (ws + 131072);
    float* dw  = (float*)(ws + 163840);
    float* sse = (float*)(ws + 8552448);
    float* ssx = (float*)(ws + 8585216);

    __bf16* X3 = (__bf16*)out;
    __bf16* E3 = (__bf16*)(out + 2 * (size_t)N_ * D_);

    hipMemsetAsync(best, 0xFF, (size_t)N_ * 8, stream);
    hipMemsetAsync(cs, 0, 8650752 - 131072, stream);   // cs+dw+sse+ssx contiguous

    prep_e_kernel<<<K_ / 4, 256, 0, stream>>>(E, E3, sse);
    prep_x_kernel<<<1024, 256, 0, stream>>>(x, X3, ssx);
    dist_kernel<<<4096, 256, 0, stream>>>(E3, X3, ssx, sse, best);
    scatter_kernel<<<256, 256, 0, stream>>>(x, E, best, out, cs, dw);
    finalize_kernel<<<K_, 256, 0, stream>>>(cs, dw, out + 3 * (size_t)N_ * D_);
}

// Round 16
// 205.291 us; speedup vs baseline: 1.0884x; 1.0884x over previous
//
#include <hip/hip_runtime.h>
#include <stdint.h>

#define B_ 8
#define D_ 256
#define T_ 2048
#define K_ 8192
#define N_ (B_*T_)   // 16384

typedef __attribute__((ext_vector_type(8))) __bf16 bf16x8;
typedef __attribute__((ext_vector_type(4))) __bf16 bf16x4;
typedef __attribute__((ext_vector_type(2))) __bf16 bf16x2;
typedef __attribute__((ext_vector_type(4))) float f32x4;

// ---------------- workspace layout ----------------
// best: u64[N]   off 0         (131072 B)
// cs:   int[K]   off 131072    (32768 B)
// dw:   f32[K*D] off 163840    (8388608 B)
// sse:  f32[K]   off 8552448   (32768 B)
// ssx:  f32[N]   off 8585216   (65536 B)
// K-slot-major panels in d_out (scratch until scatter runs):
//   X3 = [64 panels][16384 rows][8 bf16] (16.78 MB) at out+0
//        panels kh*4+s for Xh (0..31), 32+kh*4+s for Xl
//   E3 = [64 panels][8192 rows][8 bf16]  (8.39 MB)  at out+32MB
//        panels kh*4+s for El (0..31), (8+kh)*4+s for Eh (32..63)
// R15 dist: per-kh fused pair. Even phase {A-El(kh), Xh(kh)} -> El·Xh;
// odd phase {A-Eh(kh), Xl(kh)} -> Eh·Xl, then Eh·Xh with Xh frags HELD IN
// REGISTERS from the even phase. Every panel staged exactly once.
// Counted VMW(6) 2-deep pipeline (uniform 6 ops/stage), A 3-buf, Xh/Xl 2-buf,
// 80 KB LDS -> 2 blocks/CU. Per-acc order: per-kh (El·Xh, Eh·Xl, Eh·Xh) —
// ulp-class reorder of R14 (same class as all prior passing reorders).

__global__ __launch_bounds__(256) void prep_e_kernel(const float* __restrict__ E,
                                                     __bf16* __restrict__ E3,
                                                     float* __restrict__ sse) {
    int row  = blockIdx.x * 4 + (threadIdx.x >> 6);
    int lane = threadIdx.x & 63;
    int d    = lane * 4;
    float4 v = *(const float4*)(E + (size_t)row * D_ + d);
    __bf16 h0 = (__bf16)v.x, h1 = (__bf16)v.y, h2 = (__bf16)v.z, h3 = (__bf16)v.w;
    __bf16 l0 = (__bf16)(v.x - (float)h0), l1 = (__bf16)(v.y - (float)h1);
    __bf16 l2 = (__bf16)(v.z - (float)h2), l3 = (__bf16)(v.w - (float)h3);
    bf16x4 hv = {h0, h1, h2, h3};
    bf16x4 lv = {l0, l1, l2, l3};
    int kh  = d >> 5;            // k-half 0..7
    int s   = (d >> 3) & 3;      // kslot
    int pos = d & 7;             // 0 or 4
    *(bf16x4*)(E3 + ((size_t)((kh    ) * 4 + s) * K_ + row) * 8 + pos) = lv; // El
    *(bf16x4*)(E3 + ((size_t)((8 + kh) * 4 + s) * K_ + row) * 8 + pos) = hv; // Eh
    float sq = __fadd_rn(__fadd_rn(__fmul_rn(v.x, v.x), __fmul_rn(v.y, v.y)),
                         __fadd_rn(__fmul_rn(v.z, v.z), __fmul_rn(v.w, v.w)));
    #pragma unroll
    for (int off = 32; off > 0; off >>= 1) sq += __shfl_down(sq, off);
    if (lane == 0) sse[row] = sq;
}

__global__ __launch_bounds__(256) void prep_x_kernel(const float* __restrict__ x,
                                                     __bf16* __restrict__ X3,
                                                     float* __restrict__ ssx) {
    __shared__ float tile[64][65];
    __shared__ float part[64][4];
    int bidx = blockIdx.x;            // b(8) x dblk(4) x tblk(32)
    int b    = bidx >> 7;
    int dblk = (bidx >> 5) & 3;
    int tblk = bidx & 31;
    int d0 = dblk * 64, t0 = tblk * 64;
    const float* xp = x + (size_t)b * D_ * T_;
    {
        int tl = threadIdx.x & 63, th = threadIdx.x >> 6;
        float s = 0.f;
        #pragma unroll
        for (int i = 0; i < 16; i++) {
            int d = i * 4 + th;
            float v = xp[(size_t)(d0 + d) * T_ + t0 + tl];
            tile[d][tl] = v;
            s = __fadd_rn(s, __fmul_rn(v, v));
        }
        part[tl][th] = s;
    }
    __syncthreads();
    if (threadIdx.x < 64) {
        float tot = __fadd_rn(__fadd_rn(__fadd_rn(part[threadIdx.x][0],
                    part[threadIdx.x][1]), part[threadIdx.x][2]), part[threadIdx.x][3]);
        atomicAdd(ssx + b * T_ + t0 + threadIdx.x, tot);
    }
    // write phase: 16B-vector split writes
    {
        int t  = threadIdx.x & 63;
        int g0 = threadIdx.x >> 6;           // 0..3
        size_t n = (size_t)b * T_ + t0 + t;
        #pragma unroll
        for (int i = 0; i < 2; i++) {
            int dg = g0 + i * 4;             // 0..7 (8 d's each)
            int p  = (d0 >> 3) + dg;         // global k-slot panel index 0..31
            bf16x8 hv, lv;
            #pragma unroll
            for (int e = 0; e < 8; e++) {
                float v = tile[dg * 8 + e][t];
                __bf16 h = (__bf16)v;
                hv[e] = h;
                lv[e] = (__bf16)(v - (float)h);
            }
            *(bf16x8*)(X3 + ((size_t)(p     ) * N_ + n) * 8) = hv;  // Xh
            *(bf16x8*)(X3 + ((size_t)(p + 32) * N_ + n) * 8) = lv;  // Xl
        }
    }
}

// -------- 256(codes) x 128(xrows) per-kh-fused MFMA distance + argmin ------
// LDS (80 KB): A 3x16KB at 0 | Xh 2x8KB at 24576 | Xl 2x8KB at 32768 (elems)

#define GLD16(g, l) __builtin_amdgcn_global_load_lds(                           \
    (const __attribute__((address_space(1))) void*)(g),                         \
    (__attribute__((address_space(3))) void*)(l), 16, 0, 0)

#define VMW(n) do { asm volatile("s_waitcnt vmcnt(" #n ")" ::: "memory");       \
                    __builtin_amdgcn_sched_barrier(0); } while (0)
#define BAR() do { asm volatile("" ::: "memory");                               \
                   __builtin_amdgcn_s_barrier();                                \
                   asm volatile("" ::: "memory");                               \
                   __builtin_amdgcn_sched_barrier(0); } while (0)

// stage an A panel group (panel = kh for El, 8+kh for Eh): 4 ops/wave
__device__ __forceinline__ void stage_A(const __bf16* __restrict__ E3,
                                        __bf16* slot, int panel,
                                        int c0, int tid) {
    __bf16* lA = slot + ((tid >> 6) << 9);
    const __bf16* gA = E3 + ((size_t)(panel * 4) * K_ + c0 + tid) * 8;
    #pragma unroll
    for (int o = 0; o < 4; o++)
        GLD16(gA + (size_t)o * K_ * 8, lA + o * 2048);
}

// stage a B panel group (panelBase = kh*4 for Xh, 32+kh*4 for Xl): 2 ops/wave
__device__ __forceinline__ void stage_B(const __bf16* __restrict__ X3,
                                        __bf16* slot, int panelBase,
                                        int r0, int tid) {
    __bf16* lB = slot + ((tid >> 6) << 9);
    #pragma unroll
    for (int o = 0; o < 2; o++) {
        const __bf16* gB = X3 + ((size_t)(panelBase + 2 * o + (tid >> 7)) * N_
                                 + r0 + (tid & 127)) * 8;
        GLD16(gB, lB + o * 2048);
    }
}

__device__ __forceinline__ void mfma32(f32x4 acc[8][4], const bf16x8 (&af)[8],
                                       const bf16x8 (&bf)[4]) {
    __builtin_amdgcn_s_setprio(1);
    #pragma unroll
    for (int i = 0; i < 8; i++)
        #pragma unroll
        for (int j = 0; j < 4; j++)
            acc[i][j] = __builtin_amdgcn_mfma_f32_16x16x32_bf16(
                af[i], bf[j], acc[i][j], 0, 0, 0);
    __builtin_amdgcn_s_setprio(0);
}

__global__ __launch_bounds__(256, 2) void dist_kernel(
    const __bf16* __restrict__ E3, const __bf16* __restrict__ X3,
    const float* __restrict__ ssx, const float* __restrict__ sse,
    unsigned long long* __restrict__ best)
{
    extern __shared__ __bf16 smem[];   // 40960 bf16 = 80 KB

    const int tid = threadIdx.x;
    const int l   = tid & 63;
    const int w   = tid >> 6;        // 0..3
    const int wm  = w >> 1;          // code half (128 each)
    const int wn  = w & 1;           // xrow half (64 each)

    // L2-resident XCD mapping: XCD x owns c-tiles [4x,4x+4), c fastest.
    const int bid = blockIdx.x;      // 0..4095
    const int xq  = bid & 7;
    const int i_  = bid >> 3;        // 0..511
    const int c0  = (xq * 4 + (i_ & 3)) * 256;
    const int r0  = (i_ >> 2) * 128;

    f32x4 acc[8][4];
    #pragma unroll
    for (int i = 0; i < 8; i++)
        #pragma unroll
        for (int j = 0; j < 4; j++) acc[i][j] = (f32x4)0.f;

    __bf16* smA0 = smem;
    __bf16* smXh = smem + 24576;
    __bf16* smXl = smem + 32768;

    const int aoff  = (l >> 4) * 2048 + (wm * 128 + (l & 15)) * 8;
    const int boff  = (l >> 4) * 1024 + (wn * 64 + (l & 15)) * 8;

    // prolog: s0 = {El(0), Xh(0)} -> A-slot0/Xh0; s1 = {Eh(0), Xl(0)} -> A1/Xl0
    stage_A(E3, smA0 + 0 * 8192, 0, c0, tid);
    stage_B(X3, smXh + 0 * 4096, 0, r0, tid);
    stage_A(E3, smA0 + 1 * 8192, 8, c0, tid);
    stage_B(X3, smXl + 0 * 4096, 32, r0, tid);
    VMW(6);
    BAR();

    // 16 phases = 8 kh pairs; 2-deep counted pipeline, VMW(6) steady state.
    #pragma unroll
    for (int kh = 0; kh < 8; kh++) {
        const int aE = (2 * kh) % 3;       // A-slot of El(kh)
        const int aH = (2 * kh + 1) % 3;   // A-slot of Eh(kh)
        const int xs = kh & 1;             // Xh/Xl slot of kh
        bf16x8 af[8], bxh[4], bxl[4];

        // even phase p=2kh: El(kh)·Xh(kh)
        if (kh < 7) {
            stage_A(E3, smA0 + ((2 * kh + 2) % 3) * 8192, kh + 1, c0, tid);
            stage_B(X3, smXh + (xs ^ 1) * 4096, (kh + 1) * 4, r0, tid);
        }
        {
            const __bf16* pa = smA0 + aE * 8192 + aoff;
            const __bf16* pb = smXh + xs * 4096 + boff;
            #pragma unroll
            for (int i = 0; i < 8; i++) af[i] = *(const bf16x8*)(pa + i * 128);
            #pragma unroll
            for (int j = 0; j < 4; j++) bxh[j] = *(const bf16x8*)(pb + j * 128);
        }
        mfma32(acc, af, bxh);              // El·Xh
        if (kh < 7) { VMW(6); } else { VMW(0); }
        BAR();

        // odd phase p=2kh+1: Eh(kh)·Xl(kh) then Eh(kh)·Xh(kh) [bxh in regs]
        if (kh < 7) {
            stage_A(E3, smA0 + ((2 * kh + 3) % 3) * 8192, 8 + kh + 1, c0, tid);
            stage_B(X3, smXl + (xs ^ 1) * 4096, 32 + (kh + 1) * 4, r0, tid);
        }
        {
            const __bf16* pa = smA0 + aH * 8192 + aoff;
            const __bf16* pb = smXl + xs * 4096 + boff;
            #pragma unroll
            for (int i = 0; i < 8; i++) af[i] = *(const bf16x8*)(pa + i * 128);
            #pragma unroll
            for (int j = 0; j < 4; j++) bxl[j] = *(const bf16x8*)(pb + j * 128);
        }
        mfma32(acc, af, bxl);              // Eh·Xl
        mfma32(acc, af, bxh);              // Eh·Xh
        if (kh < 7) { VMW(6); BAR(); }
    }

    // epilogue: dist = (ssx + sse) - 2*dot, packed-u64 argmin (ties -> low idx)
    #pragma unroll
    for (int j = 0; j < 4; j++) {
        int xrow = r0 + wn * 64 + j * 16 + (l & 15);
        float sx = ssx[xrow];
        unsigned long long m = ~0ull;
        #pragma unroll
        for (int i = 0; i < 8; i++) {
            int cbase = c0 + wm * 128 + i * 16 + (l >> 4) * 4;
            float4 sc = *(const float4*)(sse + cbase);
            f32x4 a = acc[i][j];
            float d0 = (sx + sc.x) - 2.0f * a[0];
            float d1 = (sx + sc.y) - 2.0f * a[1];
            float d2 = (sx + sc.z) - 2.0f * a[2];
            float d3 = (sx + sc.w) - 2.0f * a[3];
            unsigned long long p;
            p = ((unsigned long long)__float_as_uint(d0) << 32) | (unsigned)(cbase + 0);
            if (p < m) m = p;
            p = ((unsigned long long)__float_as_uint(d1) << 32) | (unsigned)(cbase + 1);
            if (p < m) m = p;
            p = ((unsigned long long)__float_as_uint(d2) << 32) | (unsigned)(cbase + 2);
            if (p < m) m = p;
            p = ((unsigned long long)__float_as_uint(d3) << 32) | (unsigned)(cbase + 3);
            if (p < m) m = p;
        }
        unsigned long long o;
        o = __shfl_xor(m, 16); if (o < m) m = o;
        o = __shfl_xor(m, 32); if (o < m) m = o;
        if ((l >> 4) == 0) atomicMin(best + xrow, m);
    }
}

// tiled coalesced gather/copy/stats: block = 64 n's x 256 d's
__global__ __launch_bounds__(256) void scatter_kernel(
    const float* __restrict__ x, const float* __restrict__ E,
    const unsigned long long* __restrict__ best,
    float* __restrict__ out, int* __restrict__ cs, float* __restrict__ dw)
{
    __shared__ float tx[64][68];
    __shared__ float te[64][68];
    __shared__ int sidx[64];

    const int blk = blockIdx.x;
    const int b   = blk >> 5;
    const int t0  = (blk & 31) * 64;
    const int tid = threadIdx.x;
    const int n0  = b * T_ + t0;

    if (tid < 64) {
        int ix = (int)(best[n0 + tid] & 0xffffffffu);
        sidx[tid] = ix;
        atomicAdd(cs + ix, 1);
    }
    __syncthreads();

    const int t4   = (tid & 15) * 4;
    const int dg   = tid >> 4;
    const int l    = tid & 63;
    const int w    = tid >> 6;
    const int nsub = l >> 4;
    const int dl4  = (l & 15) * 4;

    float* o0 = out;
    float* o1 = out + (size_t)N_ * D_;
    float* o2 = out + 2 * (size_t)N_ * D_;

    for (int dc = 0; dc < 4; dc++) {
        const int d0 = dc * 64;
        #pragma unroll
        for (int r = 0; r < 4; r++) {
            int d = r * 16 + dg;
            size_t gi = ((size_t)(b * D_ + d0 + d)) * T_ + t0 + t4;
            float4 v = *(const float4*)(x + gi);
            *(float4*)&tx[d][t4] = v;
            *(float4*)(o1 + gi) = v;
        }
        #pragma unroll
        for (int i = 0; i < 4; i++) {
            int nl  = w * 16 + i * 4 + nsub;
            int row = sidx[nl];
            float4 ev = *(const float4*)(E + (size_t)row * D_ + d0 + dl4);
            te[dl4 + 0][nl] = ev.x;
            te[dl4 + 1][nl] = ev.y;
            te[dl4 + 2][nl] = ev.z;
            te[dl4 + 3][nl] = ev.w;
        }
        __syncthreads();
        #pragma unroll
        for (int r = 0; r < 4; r++) {
            int d = r * 16 + dg;
            float4 v = *(const float4*)&te[d][t4];
            size_t gi = ((size_t)(b * D_ + d0 + d)) * T_ + t0 + t4;
            *(float4*)(o0 + gi) = v;
            *(float4*)(o2 + gi) = v;
        }
        #pragma unroll
        for (int i = 0; i < 16; i++) {
            int nl = w * 16 + i;
            atomicAdd(dw + (size_t)sidx[nl] * D_ + d0 + l, tx[l][nl]);
        }
        __syncthreads();
    }
}

__global__ __launch_bounds__(256) void finalize_kernel(
    const int* __restrict__ cs, const float* __restrict__ dw,
    float* __restrict__ out3)
{
    int k = blockIdx.x;
    int d = threadIdx.x;
    const float C = 0.00999999977648258209228515625f;
    float c   = (float)cs[k];
    float ecs = (c * C) / C;
    float edw = (dw[(size_t)k * D_ + d] * C) / C;
    float n = 16384.0f;
    float denom = (ecs + 1e-5f) / (n + (float)K_ * 1e-5f) * n;
    out3[(size_t)k * D_ + d] = edw / denom;
}

extern "C" void kernel_launch(void* const* d_in, const int* in_sizes, int n_in,
                              void* d_out, int out_size, void* d_ws, size_t ws_size,
                              hipStream_t stream) {
    const float* x = (const float*)d_in[0];
    const float* E = (const float*)d_in[1];
    float* out = (float*)d_out;

    char* ws = (char*)d_ws;
    unsigned long long* best = (unsigned long long*)(ws);
    int*   cs  = (int*)  (ws + 131072);
    float* dw  = (float*)(ws + 163840);
    float* sse = (float*)(ws + 8552448);
    float* ssx = (float*)(ws + 8585216);

    __bf16* X3 = (__bf16*)out;
    __bf16* E3 = (__bf16*)(out + 2 * (size_t)N_ * D_);

    hipMemsetAsync(best, 0xFF, (size_t)N_ * 8, stream);
    hipMemsetAsync(cs, 0, 8650752 - 131072, stream);   // cs+dw+sse+ssx contiguous

    hipFuncSetAttribute((const void*)dist_kernel,
                        hipFuncAttributeMaxDynamicSharedMemorySize, 81920);

    prep_e_kernel<<<K_ / 4, 256, 0, stream>>>(E, E3, sse);
    prep_x_kernel<<<1024, 256, 0, stream>>>(x, X3, ssx);
    dist_kernel<<<4096, 256, 81920, stream>>>(E3, X3, ssx, sse, best);
    scatter_kernel<<<256, 256, 0, stream>>>(x, E, best, out, cs, dw);
    finalize_kernel<<<K_, 256, 0, stream>>>(cs, dw, out + 3 * (size_t)N_ * D_);
}

// Round 17
// 199.349 us; speedup vs baseline: 1.1208x; 1.0298x over previous
//
#include <hip/hip_runtime.h>
#include <stdint.h>

#define B_ 8
#define D_ 256
#define T_ 2048
#define K_ 8192
#define N_ (B_*T_)   // 16384

typedef __attribute__((ext_vector_type(8))) __bf16 bf16x8;
typedef __attribute__((ext_vector_type(4))) __bf16 bf16x4;
typedef __attribute__((ext_vector_type(2))) __bf16 bf16x2;
typedef __attribute__((ext_vector_type(4))) float f32x4;

// ---------------- workspace layout ----------------
// best: u64[N]   off 0         (131072 B)
// cs:   int[K]   off 131072    (32768 B)
// dw:   f32[K*D] off 163840    (8388608 B)
// sse:  f32[K]   off 8552448   (32768 B)
// ssx:  f32[N]   off 8585216   (65536 B)
// K-slot-major panels in d_out (scratch until scatter runs):
//   X3 = [64 panels][16384 rows][8 bf16] (16.78 MB) at out+0
//        panels kh*4+s for Xh (0..31), 32+kh*4+s for Xl
//   E3 = [64 panels][8192 rows][8 bf16]  (8.39 MB)  at out+32MB
//        panels kh*4+s for El (0..31), (8+kh)*4+s for Eh (32..63)
// dist (R15, measured best): per-kh fused pair; every panel staged once;
// counted VMW(6) 2-deep pipeline; A 3-buf, Xh/Xl 2-buf; 80 KB LDS ->
// 2 blocks/CU. Numerics identical to R15 (absmax 0.015625).
// R16 = R15 + fused prep kernel (prep_e ∪ prep_x ∪ best-init, one dispatch).

// fused prep: blocks 0..2047 = prep_e work (+ best init), 2048..3071 = prep_x
__global__ __launch_bounds__(256) void prep_kernel(const float* __restrict__ E,
                                                   const float* __restrict__ x,
                                                   __bf16* __restrict__ E3,
                                                   __bf16* __restrict__ X3,
                                                   float* __restrict__ sse,
                                                   float* __restrict__ ssx,
                                                   unsigned long long* __restrict__ best) {
    if (blockIdx.x < 2048) {
        // ---- prep_e body (byte-identical math) ----
        int bid  = blockIdx.x;
        // best init: first 64 blocks write 256 entries each
        int gid = bid * 256 + threadIdx.x;
        if (gid < N_) best[gid] = ~0ull;

        int row  = bid * 4 + (threadIdx.x >> 6);
        int lane = threadIdx.x & 63;
        int d    = lane * 4;
        float4 v = *(const float4*)(E + (size_t)row * D_ + d);
        __bf16 h0 = (__bf16)v.x, h1 = (__bf16)v.y, h2 = (__bf16)v.z, h3 = (__bf16)v.w;
        __bf16 l0 = (__bf16)(v.x - (float)h0), l1 = (__bf16)(v.y - (float)h1);
        __bf16 l2 = (__bf16)(v.z - (float)h2), l3 = (__bf16)(v.w - (float)h3);
        bf16x4 hv = {h0, h1, h2, h3};
        bf16x4 lv = {l0, l1, l2, l3};
        int kh  = d >> 5;            // k-half 0..7
        int s   = (d >> 3) & 3;      // kslot
        int pos = d & 7;             // 0 or 4
        *(bf16x4*)(E3 + ((size_t)((kh    ) * 4 + s) * K_ + row) * 8 + pos) = lv; // El
        *(bf16x4*)(E3 + ((size_t)((8 + kh) * 4 + s) * K_ + row) * 8 + pos) = hv; // Eh
        float sq = __fadd_rn(__fadd_rn(__fmul_rn(v.x, v.x), __fmul_rn(v.y, v.y)),
                             __fadd_rn(__fmul_rn(v.z, v.z), __fmul_rn(v.w, v.w)));
        #pragma unroll
        for (int off = 32; off > 0; off >>= 1) sq += __shfl_down(sq, off);
        if (lane == 0) sse[row] = sq;
        return;
    }
    // ---- prep_x body (byte-identical math) ----
    __shared__ float tile[64][65];
    __shared__ float part[64][4];
    int bidx = blockIdx.x - 2048;     // b(8) x dblk(4) x tblk(32)
    int b    = bidx >> 7;
    int dblk = (bidx >> 5) & 3;
    int tblk = bidx & 31;
    int d0 = dblk * 64, t0 = tblk * 64;
    const float* xp = x + (size_t)b * D_ * T_;
    {
        int tl = threadIdx.x & 63, th = threadIdx.x >> 6;
        float s = 0.f;
        #pragma unroll
        for (int i = 0; i < 16; i++) {
            int d = i * 4 + th;
            float v = xp[(size_t)(d0 + d) * T_ + t0 + tl];
            tile[d][tl] = v;
            s = __fadd_rn(s, __fmul_rn(v, v));
        }
        part[tl][th] = s;
    }
    __syncthreads();
    if (threadIdx.x < 64) {
        float tot = __fadd_rn(__fadd_rn(__fadd_rn(part[threadIdx.x][0],
                    part[threadIdx.x][1]), part[threadIdx.x][2]), part[threadIdx.x][3]);
        atomicAdd(ssx + b * T_ + t0 + threadIdx.x, tot);
    }
    {
        int t  = threadIdx.x & 63;
        int g0 = threadIdx.x >> 6;           // 0..3
        size_t n = (size_t)b * T_ + t0 + t;
        #pragma unroll
        for (int i = 0; i < 2; i++) {
            int dg = g0 + i * 4;             // 0..7 (8 d's each)
            int p  = (d0 >> 3) + dg;         // global k-slot panel index 0..31
            bf16x8 hv, lv;
            #pragma unroll
            for (int e = 0; e < 8; e++) {
                float v = tile[dg * 8 + e][t];
                __bf16 h = (__bf16)v;
                hv[e] = h;
                lv[e] = (__bf16)(v - (float)h);
            }
            *(bf16x8*)(X3 + ((size_t)(p     ) * N_ + n) * 8) = hv;  // Xh
            *(bf16x8*)(X3 + ((size_t)(p + 32) * N_ + n) * 8) = lv;  // Xl
        }
    }
}

// -------- 256(codes) x 128(xrows) per-kh-fused MFMA distance + argmin ------
// LDS (80 KB): A 3x16KB at 0 | Xh 2x8KB at 24576 | Xl 2x8KB at 32768 (elems)

#define GLD16(g, l) __builtin_amdgcn_global_load_lds(                           \
    (const __attribute__((address_space(1))) void*)(g),                         \
    (__attribute__((address_space(3))) void*)(l), 16, 0, 0)

#define VMW(n) do { asm volatile("s_waitcnt vmcnt(" #n ")" ::: "memory");       \
                    __builtin_amdgcn_sched_barrier(0); } while (0)
#define BAR() do { asm volatile("" ::: "memory");                               \
                   __builtin_amdgcn_s_barrier();                                \
                   asm volatile("" ::: "memory");                               \
                   __builtin_amdgcn_sched_barrier(0); } while (0)

__device__ __forceinline__ void stage_A(const __bf16* __restrict__ E3,
                                        __bf16* slot, int panel,
                                        int c0, int tid) {
    __bf16* lA = slot + ((tid >> 6) << 9);
    const __bf16* gA = E3 + ((size_t)(panel * 4) * K_ + c0 + tid) * 8;
    #pragma unroll
    for (int o = 0; o < 4; o++)
        GLD16(gA + (size_t)o * K_ * 8, lA + o * 2048);
}

__device__ __forceinline__ void stage_B(const __bf16* __restrict__ X3,
                                        __bf16* slot, int panelBase,
                                        int r0, int tid) {
    __bf16* lB = slot + ((tid >> 6) << 9);
    #pragma unroll
    for (int o = 0; o < 2; o++) {
        const __bf16* gB = X3 + ((size_t)(panelBase + 2 * o + (tid >> 7)) * N_
                                 + r0 + (tid & 127)) * 8;
        GLD16(gB, lB + o * 2048);
    }
}

__device__ __forceinline__ void mfma32(f32x4 acc[8][4], const bf16x8 (&af)[8],
                                       const bf16x8 (&bf)[4]) {
    __builtin_amdgcn_s_setprio(1);
    #pragma unroll
    for (int i = 0; i < 8; i++)
        #pragma unroll
        for (int j = 0; j < 4; j++)
            acc[i][j] = __builtin_amdgcn_mfma_f32_16x16x32_bf16(
                af[i], bf[j], acc[i][j], 0, 0, 0);
    __builtin_amdgcn_s_setprio(0);
}

__global__ __launch_bounds__(256, 2) void dist_kernel(
    const __bf16* __restrict__ E3, const __bf16* __restrict__ X3,
    const float* __restrict__ ssx, const float* __restrict__ sse,
    unsigned long long* __restrict__ best)
{
    extern __shared__ __bf16 smem[];   // 40960 bf16 = 80 KB

    const int tid = threadIdx.x;
    const int l   = tid & 63;
    const int w   = tid >> 6;        // 0..3
    const int wm  = w >> 1;          // code half (128 each)
    const int wn  = w & 1;           // xrow half (64 each)

    // L2-resident XCD mapping: XCD x owns c-tiles [4x,4x+4), c fastest.
    const int bid = blockIdx.x;      // 0..4095
    const int xq  = bid & 7;
    const int i_  = bid >> 3;        // 0..511
    const int c0  = (xq * 4 + (i_ & 3)) * 256;
    const int r0  = (i_ >> 2) * 128;

    f32x4 acc[8][4];
    #pragma unroll
    for (int i = 0; i < 8; i++)
        #pragma unroll
        for (int j = 0; j < 4; j++) acc[i][j] = (f32x4)0.f;

    __bf16* smA0 = smem;
    __bf16* smXh = smem + 24576;
    __bf16* smXl = smem + 32768;

    const int aoff  = (l >> 4) * 2048 + (wm * 128 + (l & 15)) * 8;
    const int boff  = (l >> 4) * 1024 + (wn * 64 + (l & 15)) * 8;

    // prolog: s0 = {El(0), Xh(0)} -> A-slot0/Xh0; s1 = {Eh(0), Xl(0)} -> A1/Xl0
    stage_A(E3, smA0 + 0 * 8192, 0, c0, tid);
    stage_B(X3, smXh + 0 * 4096, 0, r0, tid);
    stage_A(E3, smA0 + 1 * 8192, 8, c0, tid);
    stage_B(X3, smXl + 0 * 4096, 32, r0, tid);
    VMW(6);
    BAR();

    // 16 phases = 8 kh pairs; 2-deep counted pipeline, VMW(6) steady state.
    #pragma unroll
    for (int kh = 0; kh < 8; kh++) {
        const int aE = (2 * kh) % 3;       // A-slot of El(kh)
        const int aH = (2 * kh + 1) % 3;   // A-slot of Eh(kh)
        const int xs = kh & 1;             // Xh/Xl slot of kh
        bf16x8 af[8], bxh[4], bxl[4];

        // even phase p=2kh: El(kh)·Xh(kh)
        if (kh < 7) {
            stage_A(E3, smA0 + ((2 * kh + 2) % 3) * 8192, kh + 1, c0, tid);
            stage_B(X3, smXh + (xs ^ 1) * 4096, (kh + 1) * 4, r0, tid);
        }
        {
            const __bf16* pa = smA0 + aE * 8192 + aoff;
            const __bf16* pb = smXh + xs * 4096 + boff;
            #pragma unroll
            for (int i = 0; i < 8; i++) af[i] = *(const bf16x8*)(pa + i * 128);
            #pragma unroll
            for (int j = 0; j < 4; j++) bxh[j] = *(const bf16x8*)(pb + j * 128);
        }
        mfma32(acc, af, bxh);              // El·Xh
        if (kh < 7) { VMW(6); } else { VMW(0); }
        BAR();

        // odd phase p=2kh+1: Eh(kh)·Xl(kh) then Eh(kh)·Xh(kh) [bxh in regs]
        if (kh < 7) {
            stage_A(E3, smA0 + ((2 * kh + 3) % 3) * 8192, 8 + kh + 1, c0, tid);
            stage_B(X3, smXl + (xs ^ 1) * 4096, 32 + (kh + 1) * 4, r0, tid);
        }
        {
            const __bf16* pa = smA0 + aH * 8192 + aoff;
            const __bf16* pb = smXl + xs * 4096 + boff;
            #pragma unroll
            for (int i = 0; i < 8; i++) af[i] = *(const bf16x8*)(pa + i * 128);
            #pragma unroll
            for (int j = 0; j < 4; j++) bxl[j] = *(const bf16x8*)(pb + j * 128);
        }
        mfma32(acc, af, bxl);              // Eh·Xl
        mfma32(acc, af, bxh);              // Eh·Xh
        if (kh < 7) { VMW(6); BAR(); }
    }

    // epilogue: dist = (ssx + sse) - 2*dot, packed-u64 argmin (ties -> low idx)
    #pragma unroll
    for (int j = 0; j < 4; j++) {
        int xrow = r0 + wn * 64 + j * 16 + (l & 15);
        float sx = ssx[xrow];
        unsigned long long m = ~0ull;
        #pragma unroll
        for (int i = 0; i < 8; i++) {
            int cbase = c0 + wm * 128 + i * 16 + (l >> 4) * 4;
            float4 sc = *(const float4*)(sse + cbase);
            f32x4 a = acc[i][j];
            float d0 = (sx + sc.x) - 2.0f * a[0];
            float d1 = (sx + sc.y) - 2.0f * a[1];
            float d2 = (sx + sc.z) - 2.0f * a[2];
            float d3 = (sx + sc.w) - 2.0f * a[3];
            unsigned long long p;
            p = ((unsigned long long)__float_as_uint(d0) << 32) | (unsigned)(cbase + 0);
            if (p < m) m = p;
            p = ((unsigned long long)__float_as_uint(d1) << 32) | (unsigned)(cbase + 1);
            if (p < m) m = p;
            p = ((unsigned long long)__float_as_uint(d2) << 32) | (unsigned)(cbase + 2);
            if (p < m) m = p;
            p = ((unsigned long long)__float_as_uint(d3) << 32) | (unsigned)(cbase + 3);
            if (p < m) m = p;
        }
        unsigned long long o;
        o = __shfl_xor(m, 16); if (o < m) m = o;
        o = __shfl_xor(m, 32); if (o < m) m = o;
        if ((l >> 4) == 0) atomicMin(best + xrow, m);
    }
}

// tiled coalesced gather/copy/stats: block = 64 n's x 256 d's
__global__ __launch_bounds__(256) void scatter_kernel(
    const float* __restrict__ x, const float* __restrict__ E,
    const unsigned long long* __restrict__ best,
    float* __restrict__ out, int* __restrict__ cs, float* __restrict__ dw)
{
    __shared__ float tx[64][68];
    __shared__ float te[64][68];
    __shared__ int sidx[64];

    const int blk = blockIdx.x;
    const int b   = blk >> 5;
    const int t0  = (blk & 31) * 64;
    const int tid = threadIdx.x;
    const int n0  = b * T_ + t0;

    if (tid < 64) {
        int ix = (int)(best[n0 + tid] & 0xffffffffu);
        sidx[tid] = ix;
        atomicAdd(cs + ix, 1);
    }
    __syncthreads();

    const int t4   = (tid & 15) * 4;
    const int dg   = tid >> 4;
    const int l    = tid & 63;
    const int w    = tid >> 6;
    const int nsub = l >> 4;
    const int dl4  = (l & 15) * 4;

    float* o0 = out;
    float* o1 = out + (size_t)N_ * D_;
    float* o2 = out + 2 * (size_t)N_ * D_;

    for (int dc = 0; dc < 4; dc++) {
        const int d0 = dc * 64;
        #pragma unroll
        for (int r = 0; r < 4; r++) {
            int d = r * 16 + dg;
            size_t gi = ((size_t)(b * D_ + d0 + d)) * T_ + t0 + t4;
            float4 v = *(const float4*)(x + gi);
            *(float4*)&tx[d][t4] = v;
            *(float4*)(o1 + gi) = v;
        }
        #pragma unroll
        for (int i = 0; i < 4; i++) {
            int nl  = w * 16 + i * 4 + nsub;
            int row = sidx[nl];
            float4 ev = *(const float4*)(E + (size_t)row * D_ + d0 + dl4);
            te[dl4 + 0][nl] = ev.x;
            te[dl4 + 1][nl] = ev.y;
            te[dl4 + 2][nl] = ev.z;
            te[dl4 + 3][nl] = ev.w;
        }
        __syncthreads();
        #pragma unroll
        for (int r = 0; r < 4; r++) {
            int d = r * 16 + dg;
            float4 v = *(const float4*)&te[d][t4];
            size_t gi = ((size_t)(b * D_ + d0 + d)) * T_ + t0 + t4;
            *(float4*)(o0 + gi) = v;
            *(float4*)(o2 + gi) = v;
        }
        #pragma unroll
        for (int i = 0; i < 16; i++) {
            int nl = w * 16 + i;
            atomicAdd(dw + (size_t)sidx[nl] * D_ + d0 + l, tx[l][nl]);
        }
        __syncthreads();
    }
}

__global__ __launch_bounds__(256) void finalize_kernel(
    const int* __restrict__ cs, const float* __restrict__ dw,
    float* __restrict__ out3)
{
    int k = blockIdx.x;
    int d = threadIdx.x;
    const float C = 0.00999999977648258209228515625f;
    float c   = (float)cs[k];
    float ecs = (c * C) / C;
    float edw = (dw[(size_t)k * D_ + d] * C) / C;
    float n = 16384.0f;
    float denom = (ecs + 1e-5f) / (n + (float)K_ * 1e-5f) * n;
    out3[(size_t)k * D_ + d] = edw / denom;
}

extern "C" void kernel_launch(void* const* d_in, const int* in_sizes, int n_in,
                              void* d_out, int out_size, void* d_ws, size_t ws_size,
                              hipStream_t stream) {
    const float* x = (const float*)d_in[0];
    const float* E = (const float*)d_in[1];
    float* out = (float*)d_out;

    char* ws = (char*)d_ws;
    unsigned long long* best = (unsigned long long*)(ws);
    int*   cs  = (int*)  (ws + 131072);
    float* dw  = (float*)(ws + 163840);
    float* sse = (float*)(ws + 8552448);
    float* ssx = (float*)(ws + 8585216);

    __bf16* X3 = (__bf16*)out;
    __bf16* E3 = (__bf16*)(out + 2 * (size_t)N_ * D_);

    // one memset covers cs + dw + sse + ssx; best is 0xFF-init inside prep
    hipMemsetAsync(cs, 0, 8650752 - 131072, stream);

    hipFuncSetAttribute((const void*)dist_kernel,
                        hipFuncAttributeMaxDynamicSharedMemorySize, 81920);

    prep_kernel<<<3072, 256, 0, stream>>>(E, x, E3, X3, sse, ssx, best);
    dist_kernel<<<4096, 256, 81920, stream>>>(E3, X3, ssx, sse, best);
    scatter_kernel<<<256, 256, 0, stream>>>(x, E, best, out, cs, dw);
    finalize_kernel<<<K_, 256, 0, stream>>>(cs, dw, out + 3 * (size_t)N_ * D_);
}